// Round 3
// baseline (410.850 us; speedup 1.0000x reference)
//
#include <hip/hip_runtime.h>
#include <hip/hip_cooperative_groups.h>

namespace cg = cooperative_groups;

#define NN     4096
#define TT     3
#define DD     20
#define EE     131072
#define ADIM   128
#define NHEADS 2
#define NEG    0.2f
#define WPR    (NN / 8)   // 512 uint32 mask words per row (4 bits per ordered pair)
#define NBLK   1024
#define NTHR   256

// One GNN layer: 4 rows per block (one row per wave). lut/S computed per block.
__device__ __forceinline__ void layer_phase(const unsigned int* __restrict__ mask,
                                            const float* __restrict__ s_in,
                                            const float* __restrict__ att_w,
                                            const float* __restrict__ edge_emb,
                                            float* __restrict__ s_out,
                                            int layer, int tid, int bid) {
    __shared__ float lut[NHEADS][8];
    __shared__ float w0s[NHEADS], wNs[NHEADS];
    __shared__ float Sred[4];
    int wid = tid >> 6, lane = tid & 63;

    if (tid < NHEADS * 8) {
        int h = tid >> 3, m = tid & 7;
        const float* w = att_w + (layer * NHEADS + h) * (DD + 2);
        float e0 = 0.f, e1 = 0.f, e2 = 0.f;
        #pragma unroll
        for (int d = 0; d < DD; d++) {
            float wd = w[1 + d];
            e0 += edge_emb[0 * DD + d] * wd;
            e1 += edge_emb[1 * DD + d] * wd;
            e2 += edge_emb[2 * DD + d] * wd;
        }
        lut[h][m] = (m & 1 ? e0 : 0.f) + (m & 2 ? e1 : 0.f) + (m & 4 ? e2 : 0.f);
        if (m == 0) { w0s[h] = w[0]; wNs[h] = w[DD + 1]; }
    }

    // Block-level S = sum(s_in) (16 KB, L2-resident; deterministic).
    float ps = 0.f;
    for (int j = tid; j < NN; j += NTHR) ps += s_in[j];
    #pragma unroll
    for (int off = 32; off > 0; off >>= 1) ps += __shfl_down(ps, off);
    if (lane == 0) Sred[wid] = ps;
    __syncthreads();
    float S = Sred[0] + Sred[1] + Sred[2] + Sred[3];

    int row = bid * 4 + wid;
    float si = s_in[row];
    const unsigned int* mrow = mask + (size_t)row * WPR;
    float a0 = w0s[0] * si, a1 = w0s[1] * si;
    float b0 = wNs[0],      b1 = wNs[1];

    // Load all 8 mask words up front (independent loads -> ILP).
    unsigned int mw[8];
    #pragma unroll
    for (int k = 0; k < 8; k++) mw[k] = mrow[k * 64 + lane];

    float num0 = 0.f, den0 = 0.f, num1 = 0.f, den1 = 0.f;
    #pragma unroll
    for (int k = 0; k < 8; k++) {
        unsigned int m = mw[k];
        if (m == 0u) continue;
        int jbase = (k * 64 + lane) << 3;
        #pragma unroll
        for (int kk = 0; kk < 8; kk++) {
            unsigned int nib = (m >> (kk * 4)) & 0xFu;
            if (!nib) continue;
            float c  = (float)__popc(nib);
            float sj = s_in[jbase + kk];
            float l0 = c * (a0 + b0 * sj) + lut[0][nib];
            l0 = (l0 > 0.f) ? l0 : NEG * l0;
            float e0 = __expf(l0) - 1.0f;
            num0 += e0 * sj; den0 += e0;
            float l1 = c * (a1 + b1 * sj) + lut[1][nib];
            l1 = (l1 > 0.f) ? l1 : NEG * l1;
            float e1 = __expf(l1) - 1.0f;
            num1 += e1 * sj; den1 += e1;
        }
    }

    // Wave-level reduction (one row per wave; no block reduce needed).
    #pragma unroll
    for (int off = 32; off > 0; off >>= 1) {
        num0 += __shfl_down(num0, off); den0 += __shfl_down(den0, off);
        num1 += __shfl_down(num1, off); den1 += __shfl_down(den1, off);
    }
    if (lane == 0) {
        float o0 = (S + num0) / ((float)NN + den0);
        float o1 = (S + num1) / ((float)NN + den1);
        s_out[row] = 0.5f * (o0 + o1);
    }
}

__global__ __launch_bounds__(NTHR) void k_fused(const float* __restrict__ inputs,
                                                const float* __restrict__ lin_w,
                                                const float* __restrict__ lin_b,
                                                const float* __restrict__ edge_emb,
                                                const float* __restrict__ att_w,
                                                const int* __restrict__ el,
                                                unsigned int* __restrict__ mask,
                                                float* __restrict__ s0,
                                                float* __restrict__ s1,
                                                float* __restrict__ out) {
    cg::grid_group grid = cg::this_grid();
    int tid = threadIdx.x;
    int bid = blockIdx.x;
    int gid = bid * NTHR + tid;
    int wid = tid >> 6, lane = tid & 63;

    // ---- P0: zero the 8 MB mask (2 uint4 per thread) + init scores ----------
    uint4* mask4 = (uint4*)mask;
    mask4[gid] = make_uint4(0u, 0u, 0u, 0u);
    mask4[gid + NBLK * NTHR] = make_uint4(0u, 0u, 0u, 0u);
    {
        int row = bid * 4 + wid;                  // 4096 waves = 4096 rows
        const float* rp = inputs + row * ADIM;
        float v = rp[lane] * lin_w[lane] + rp[lane + 64] * lin_w[lane + 64];
        #pragma unroll
        for (int off = 32; off > 0; off >>= 1) v += __shfl_down(v, off);
        if (lane == 0) s0[row] = v + lin_b[0];
    }
    grid.sync();

    // ---- P1: scatter edges into 4-bit-per-pair type bitmask ------------------
    for (int i = gid; i < TT * EE; i += NBLK * NTHR) {
        int t = i / EE;                            // EE = 2^17 -> shift
        int e = i - t * EE;
        unsigned int src = (unsigned int)el[t * 2 * EE + e];
        unsigned int tgt = (unsigned int)el[t * 2 * EE + EE + e];
        unsigned int p1 = src * NN + tgt;
        unsigned int p2 = tgt * NN + src;
        atomicOr(&mask[p1 >> 3], 1u << (((p1 & 7u) << 2) + (unsigned)t));
        atomicOr(&mask[p2 >> 3], 1u << (((p2 & 7u) << 2) + (unsigned)t));
    }
    grid.sync();

    // ---- P2: layer 0 ---------------------------------------------------------
    layer_phase(mask, s0, att_w, edge_emb, s1, 0, tid, bid);
    grid.sync();

    // ---- P3: layer 1 ---------------------------------------------------------
    layer_phase(mask, s1, att_w, edge_emb, out, 1, tid, bid);
}

// ---------------- host-side launcher -----------------------------------------
extern "C" void kernel_launch(void* const* d_in, const int* in_sizes, int n_in,
                              void* d_out, int out_size, void* d_ws, size_t ws_size,
                              hipStream_t stream) {
    const float* inputs   = (const float*)d_in[0];
    const float* lin_w    = (const float*)d_in[1];
    const float* lin_b    = (const float*)d_in[2];
    const float* edge_emb = (const float*)d_in[3];
    const float* att_w    = (const float*)d_in[4];
    const int*   el       = (const int*)d_in[5];
    float* out = (float*)d_out;

    char* ws = (char*)d_ws;
    unsigned int* mask = (unsigned int*)ws;                       // 8 MB
    float* s0   = (float*)(ws + 8u * 1024u * 1024u);              // 16 KB
    float* s1   = (float*)(ws + 8u * 1024u * 1024u + 16384u);     // 16 KB

    void* args[] = { (void*)&inputs, (void*)&lin_w, (void*)&lin_b,
                     (void*)&edge_emb, (void*)&att_w, (void*)&el,
                     (void*)&mask, (void*)&s0, (void*)&s1, (void*)&out };
    hipLaunchCooperativeKernel((const void*)k_fused, dim3(NBLK), dim3(NTHR),
                               args, 0, stream);
}

// Round 4
// 130.109 us; speedup vs baseline: 3.1577x; 3.1577x over previous
//
#include <hip/hip_runtime.h>

#define NN     4096
#define TT     3
#define DD     20
#define EE     131072
#define ADIM   128
#define NEG    0.2f
#define NINST  (TT * EE)               // 393216 edge instances
#define TRI    ((NN * (NN + 1)) / 2)   // 8390656 unordered-pair slots
#define TRIW   ((TRI + 7) / 8)         // 1048832 mask words (4 bits/slot)
#define TRIW4  ((TRIW + 3) / 4)        // 262208 uint4
#define CAP    512                     // entries per row (mean ~181, max ~250)

// ---- k0: zero mask + counters, init scores s0 = inputs@lin_w.T + lin_b ------
__global__ __launch_bounds__(256) void k_init(uint4* __restrict__ mask4,
                                              unsigned int* __restrict__ cnt,
                                              const float* __restrict__ inputs,
                                              const float* __restrict__ lin_w,
                                              const float* __restrict__ lin_b,
                                              float* __restrict__ s0) {
    int tid = threadIdx.x, bid = blockIdx.x;
    int gid = bid * 256 + tid;
    for (int i = gid; i < TRIW4; i += 1024 * 256)
        mask4[i] = make_uint4(0u, 0u, 0u, 0u);
    if (gid < NN) cnt[gid] = 0u;

    int wid = tid >> 6, lane = tid & 63;
    int row = bid * 4 + wid;                       // 1024 blocks * 4 waves = 4096 rows
    const float* rp = inputs + row * ADIM;
    float v = rp[lane] * lin_w[lane] + rp[lane + 64] * lin_w[lane + 64];
    #pragma unroll
    for (int off = 32; off > 0; off >>= 1) v += __shfl_down(v, off);
    if (lane == 0) s0[row] = v + lin_b[0];
}

// ---- k1: scatter types into triangle nibble-mask; record bit-inserters ------
__global__ __launch_bounds__(256) void k_scatter(const int* __restrict__ el,
                                                 unsigned int* __restrict__ mask,
                                                 unsigned char* __restrict__ flags) {
    int i = blockIdx.x * 256 + threadIdx.x;        // exactly NINST threads
    int t = i >> 17;                               // EE = 2^17
    int e = i & (EE - 1);
    unsigned int src = (unsigned int)el[(t * 2) * EE + e];
    unsigned int tgt = (unsigned int)el[(t * 2 + 1) * EE + e];
    unsigned int lo = min(src, tgt), hi = max(src, tgt);
    unsigned int slot = ((hi * (hi + 1)) >> 1) + lo;
    unsigned int sh = ((slot & 7u) << 2) + (unsigned int)t;
    unsigned int old = atomicOr(&mask[slot >> 3], 1u << sh);
    flags[i] = (unsigned char)(((old >> sh) & 1u) ^ 1u);   // 1 iff we inserted the bit
}

// ---- k2: pair owners append CSR entries (j | nib<<12) to both endpoint rows -
__global__ __launch_bounds__(256) void k_build(const int* __restrict__ el,
                                               const unsigned int* __restrict__ mask,
                                               const unsigned char* __restrict__ flags,
                                               unsigned int* __restrict__ cnt,
                                               unsigned short* __restrict__ entries) {
    int i = blockIdx.x * 256 + threadIdx.x;
    if (!flags[i]) return;
    int t = i >> 17;
    int e = i & (EE - 1);
    unsigned int src = (unsigned int)el[(t * 2) * EE + e];
    unsigned int tgt = (unsigned int)el[(t * 2 + 1) * EE + e];
    unsigned int lo = min(src, tgt), hi = max(src, tgt);
    unsigned int slot = ((hi * (hi + 1)) >> 1) + lo;
    unsigned int nib = (mask[slot >> 3] >> ((slot & 7u) << 2)) & 0xFu;
    // owner = inserter of the lowest set bit of the final nibble (exactly one)
    if ((nib & (unsigned int)(-(int)nib)) != (1u << t)) return;
    unsigned int idx = atomicAdd(&cnt[lo], 1u);
    if (idx < CAP) entries[lo * CAP + idx] = (unsigned short)(hi | (nib << 12));
    if (lo != hi) {
        unsigned int idx2 = atomicAdd(&cnt[hi], 1u);
        if (idx2 < CAP) entries[hi * CAP + idx2] = (unsigned short)(lo | (nib << 12));
    }
}

// ---- k3: one GNN layer over CSR (both heads + S-sum fused), row per wave ----
__global__ __launch_bounds__(256) void k_layer(const unsigned int* __restrict__ cnt,
                                               const unsigned short* __restrict__ entries,
                                               const float* __restrict__ s_in,
                                               const float* __restrict__ att_w,
                                               const float* __restrict__ edge_emb,
                                               float* __restrict__ s_out,
                                               int layer) {
    __shared__ float lut0[8], lut1[8], wc[4], Sred[4];
    int tid = threadIdx.x;

    if (tid < 16) {
        int h = tid >> 3, m = tid & 7;
        const float* w = att_w + (layer * 2 + h) * (DD + 2);
        float e0 = 0.f, e1 = 0.f, e2 = 0.f;
        #pragma unroll
        for (int d = 0; d < DD; d++) {
            float wd = w[1 + d];
            e0 += edge_emb[0 * DD + d] * wd;
            e1 += edge_emb[1 * DD + d] * wd;
            e2 += edge_emb[2 * DD + d] * wd;
        }
        float l = (m & 1 ? e0 : 0.f) + (m & 2 ? e1 : 0.f) + (m & 4 ? e2 : 0.f);
        if (h) lut1[m] = l; else lut0[m] = l;
        if (m == 0) { wc[h] = w[0]; wc[2 + h] = w[DD + 1]; }
    }

    // Block-level S = sum(s_in) (16 KB, cache-resident, deterministic).
    float ps = 0.f;
    for (int j = tid; j < NN; j += 256) ps += s_in[j];
    #pragma unroll
    for (int off = 32; off > 0; off >>= 1) ps += __shfl_down(ps, off);
    int wid = tid >> 6, lane = tid & 63;
    if (lane == 0) Sred[wid] = ps;
    __syncthreads();
    float S = Sred[0] + Sred[1] + Sred[2] + Sred[3];

    int row = blockIdx.x * 4 + wid;
    float si = s_in[row];
    float a0 = wc[0] * si, a1 = wc[1] * si;
    float b0 = wc[2],      b1 = wc[3];
    unsigned int n = min(cnt[row], (unsigned int)CAP);
    const unsigned short* ent = entries + (size_t)row * CAP;

    float num0 = 0.f, den0 = 0.f, num1 = 0.f, den1 = 0.f;
    for (unsigned int i = lane; i < n; i += 64) {
        unsigned int v = ent[i];
        unsigned int j = v & 0xFFFu, nib = v >> 12;
        float c  = (float)__popc(nib);
        float sj = s_in[j];
        float l0 = c * (a0 + b0 * sj) + lut0[nib];
        l0 = (l0 > 0.f) ? l0 : NEG * l0;
        float x0 = __expf(l0) - 1.0f;
        num0 += x0 * sj; den0 += x0;
        float l1 = c * (a1 + b1 * sj) + lut1[nib];
        l1 = (l1 > 0.f) ? l1 : NEG * l1;
        float x1 = __expf(l1) - 1.0f;
        num1 += x1 * sj; den1 += x1;
    }

    #pragma unroll
    for (int off = 32; off > 0; off >>= 1) {
        num0 += __shfl_down(num0, off); den0 += __shfl_down(den0, off);
        num1 += __shfl_down(num1, off); den1 += __shfl_down(den1, off);
    }
    if (lane == 0) {
        float o0 = (S + num0) / ((float)NN + den0);
        float o1 = (S + num1) / ((float)NN + den1);
        s_out[row] = 0.5f * (o0 + o1);
    }
}

// ---- host-side launcher ------------------------------------------------------
extern "C" void kernel_launch(void* const* d_in, const int* in_sizes, int n_in,
                              void* d_out, int out_size, void* d_ws, size_t ws_size,
                              hipStream_t stream) {
    const float* inputs   = (const float*)d_in[0];
    const float* lin_w    = (const float*)d_in[1];
    const float* lin_b    = (const float*)d_in[2];
    const float* edge_emb = (const float*)d_in[3];
    const float* att_w    = (const float*)d_in[4];
    const int*   el       = (const int*)d_in[5];
    float* out = (float*)d_out;

    char* ws = (char*)d_ws;
    unsigned int*   mask    = (unsigned int*)ws;                          // 4.2 MB
    unsigned int*   cnt     = (unsigned int*)(ws + 4456448);              // 16 KB
    unsigned short* entries = (unsigned short*)(ws + 4472832);            // 4 MB
    unsigned char*  flags   = (unsigned char*)(ws + 8667136);             // 384 KB
    float*          s0      = (float*)(ws + 9060352);                     // 16 KB
    float*          s1      = (float*)(ws + 9076736);                     // 16 KB

    k_init   <<<1024, 256, 0, stream>>>((uint4*)mask, cnt, inputs, lin_w, lin_b, s0);
    k_scatter<<<NINST / 256, 256, 0, stream>>>(el, mask, flags);
    k_build  <<<NINST / 256, 256, 0, stream>>>(el, mask, flags, cnt, entries);
    k_layer  <<<1024, 256, 0, stream>>>(cnt, entries, s0, att_w, edge_emb, s1, 0);
    k_layer  <<<1024, 256, 0, stream>>>(cnt, entries, s1, att_w, edge_emb, out, 1);
}

// Round 5
// 84.080 us; speedup vs baseline: 4.8864x; 1.5475x over previous
//
#include <hip/hip_runtime.h>

#define NN     4096
#define TT     3
#define DD     20
#define EE     131072
#define ADIM   128
#define NEG    0.2f
#define NINST  (TT * EE)               // 393216 edge instances
#define TRI    ((NN * (NN + 1)) / 2)   // 8390656 unordered-pair slots
#define TRIW   ((TRI + 7) / 8)         // 1048832 mask words (4 bits/slot)
#define TRIW4  ((TRIW + 3) / 4)        // 262208 uint4
#define CAP    512                     // entries per row (mean ~181)
#define CSTR   16                      // cnt stride in u32 -> one 64B line per row

// ---- k0: zero mask + counters, init scores s0 = inputs@lin_w.T + lin_b ------
__global__ __launch_bounds__(256) void k_init(uint4* __restrict__ mask4,
                                              unsigned int* __restrict__ cnt,
                                              const float* __restrict__ inputs,
                                              const float* __restrict__ lin_w,
                                              const float* __restrict__ lin_b,
                                              float* __restrict__ s0) {
    int tid = threadIdx.x, bid = blockIdx.x;
    int gid = bid * 256 + tid;
    for (int i = gid; i < TRIW4; i += 1024 * 256)
        mask4[i] = make_uint4(0u, 0u, 0u, 0u);
    uint4* cnt4 = (uint4*)cnt;                     // NN*CSTR u32 = 16384 uint4
    for (int i = gid; i < NN * CSTR / 4; i += 1024 * 256)
        cnt4[i] = make_uint4(0u, 0u, 0u, 0u);

    int wid = tid >> 6, lane = tid & 63;
    int row = bid * 4 + wid;                       // 1024 blocks * 4 waves = 4096 rows
    const float* rp = inputs + row * ADIM;
    float v = rp[lane] * lin_w[lane] + rp[lane + 64] * lin_w[lane + 64];
    #pragma unroll
    for (int off = 32; off > 0; off >>= 1) v += __shfl_down(v, off);
    if (lane == 0) s0[row] = v + lin_b[0];
}

// ---- k1: scatter types into triangle nibble-mask; record bit-inserters ------
__global__ __launch_bounds__(256) void k_scatter(const int* __restrict__ el,
                                                 unsigned int* __restrict__ mask,
                                                 unsigned char* __restrict__ flags) {
    int i = blockIdx.x * 256 + threadIdx.x;        // exactly NINST threads
    int t = i >> 17;                               // EE = 2^17
    int e = i & (EE - 1);
    unsigned int src = (unsigned int)el[(t * 2) * EE + e];
    unsigned int tgt = (unsigned int)el[(t * 2 + 1) * EE + e];
    unsigned int lo = min(src, tgt), hi = max(src, tgt);
    unsigned int slot = ((hi * (hi + 1)) >> 1) + lo;
    unsigned int sh = ((slot & 7u) << 2) + (unsigned int)t;
    unsigned int old = atomicOr(&mask[slot >> 3], 1u << sh);
    flags[i] = (unsigned char)(((old >> sh) & 1u) ^ 1u);   // 1 iff we inserted the bit
}

// ---- k2: pair owners append CSR entries (j | nib<<12) to both endpoint rows -
__global__ __launch_bounds__(256) void k_build(const int* __restrict__ el,
                                               const unsigned int* __restrict__ mask,
                                               const unsigned char* __restrict__ flags,
                                               unsigned int* __restrict__ cnt,
                                               unsigned short* __restrict__ entries) {
    int i = blockIdx.x * 256 + threadIdx.x;
    if (!flags[i]) return;
    int t = i >> 17;
    int e = i & (EE - 1);
    unsigned int src = (unsigned int)el[(t * 2) * EE + e];
    unsigned int tgt = (unsigned int)el[(t * 2 + 1) * EE + e];
    unsigned int lo = min(src, tgt), hi = max(src, tgt);
    unsigned int slot = ((hi * (hi + 1)) >> 1) + lo;
    unsigned int nib = (mask[slot >> 3] >> ((slot & 7u) << 2)) & 0xFu;
    // owner = inserter of the lowest set bit of the final nibble (exactly one)
    if ((nib & (unsigned int)(-(int)nib)) != (1u << t)) return;
    unsigned int idx = atomicAdd(&cnt[lo * CSTR], 1u);
    if (idx < CAP) entries[lo * CAP + idx] = (unsigned short)(hi | (nib << 12));
    if (lo != hi) {
        unsigned int idx2 = atomicAdd(&cnt[hi * CSTR], 1u);
        if (idx2 < CAP) entries[hi * CAP + idx2] = (unsigned short)(lo | (nib << 12));
    }
}

// ---- k3: one GNN layer over CSR (both heads + S-sum fused), row per wave ----
__global__ __launch_bounds__(256) void k_layer(const unsigned int* __restrict__ cnt,
                                               const unsigned short* __restrict__ entries,
                                               const float* __restrict__ s_in,
                                               const float* __restrict__ att_w,
                                               const float* __restrict__ edge_emb,
                                               float* __restrict__ s_out,
                                               int layer) {
    __shared__ float lut0[8], lut1[8], wc[4], Sred[4];
    int tid = threadIdx.x;

    if (tid < 16) {
        int h = tid >> 3, m = tid & 7;
        const float* w = att_w + (layer * 2 + h) * (DD + 2);
        float e0 = 0.f, e1 = 0.f, e2 = 0.f;
        #pragma unroll
        for (int d = 0; d < DD; d++) {
            float wd = w[1 + d];
            e0 += edge_emb[0 * DD + d] * wd;
            e1 += edge_emb[1 * DD + d] * wd;
            e2 += edge_emb[2 * DD + d] * wd;
        }
        float l = (m & 1 ? e0 : 0.f) + (m & 2 ? e1 : 0.f) + (m & 4 ? e2 : 0.f);
        if (h) lut1[m] = l; else lut0[m] = l;
        if (m == 0) { wc[h] = w[0]; wc[2 + h] = w[DD + 1]; }
    }

    // Block-level S = sum(s_in) (16 KB, cache-resident, deterministic).
    float ps = 0.f;
    for (int j = tid; j < NN; j += 256) ps += s_in[j];
    #pragma unroll
    for (int off = 32; off > 0; off >>= 1) ps += __shfl_down(ps, off);
    int wid = tid >> 6, lane = tid & 63;
    if (lane == 0) Sred[wid] = ps;
    __syncthreads();
    float S = Sred[0] + Sred[1] + Sred[2] + Sred[3];

    int row = blockIdx.x * 4 + wid;
    float si = s_in[row];
    float a0 = wc[0] * si, a1 = wc[1] * si;
    float b0 = wc[2],      b1 = wc[3];
    unsigned int n = min(cnt[row * CSTR], (unsigned int)CAP);
    const unsigned short* ent = entries + (size_t)row * CAP;

    float num0 = 0.f, den0 = 0.f, num1 = 0.f, den1 = 0.f;
    for (unsigned int i = lane; i < n; i += 64) {
        unsigned int v = ent[i];
        unsigned int j = v & 0xFFFu, nib = v >> 12;
        float c  = (float)__popc(nib);
        float sj = s_in[j];
        float l0 = c * (a0 + b0 * sj) + lut0[nib];
        l0 = (l0 > 0.f) ? l0 : NEG * l0;
        float x0 = __expf(l0) - 1.0f;
        num0 += x0 * sj; den0 += x0;
        float l1 = c * (a1 + b1 * sj) + lut1[nib];
        l1 = (l1 > 0.f) ? l1 : NEG * l1;
        float x1 = __expf(l1) - 1.0f;
        num1 += x1 * sj; den1 += x1;
    }

    #pragma unroll
    for (int off = 32; off > 0; off >>= 1) {
        num0 += __shfl_down(num0, off); den0 += __shfl_down(den0, off);
        num1 += __shfl_down(num1, off); den1 += __shfl_down(den1, off);
    }
    if (lane == 0) {
        float o0 = (S + num0) / ((float)NN + den0);
        float o1 = (S + num1) / ((float)NN + den1);
        s_out[row] = 0.5f * (o0 + o1);
    }
}

// ---- host-side launcher ------------------------------------------------------
extern "C" void kernel_launch(void* const* d_in, const int* in_sizes, int n_in,
                              void* d_out, int out_size, void* d_ws, size_t ws_size,
                              hipStream_t stream) {
    const float* inputs   = (const float*)d_in[0];
    const float* lin_w    = (const float*)d_in[1];
    const float* lin_b    = (const float*)d_in[2];
    const float* edge_emb = (const float*)d_in[3];
    const float* att_w    = (const float*)d_in[4];
    const int*   el       = (const int*)d_in[5];
    float* out = (float*)d_out;

    char* ws = (char*)d_ws;
    unsigned int*   mask    = (unsigned int*)ws;                          // 4.2 MB
    unsigned int*   cnt     = (unsigned int*)(ws + 4456448);              // 256 KB (padded)
    unsigned short* entries = (unsigned short*)(ws + 4718592);            // 4 MB
    unsigned char*  flags   = (unsigned char*)(ws + 8912896);             // 384 KB
    float*          s0      = (float*)(ws + 9306112);                     // 16 KB
    float*          s1      = (float*)(ws + 9322496);                     // 16 KB

    k_init   <<<1024, 256, 0, stream>>>((uint4*)mask, cnt, inputs, lin_w, lin_b, s0);
    k_scatter<<<NINST / 256, 256, 0, stream>>>(el, mask, flags);
    k_build  <<<NINST / 256, 256, 0, stream>>>(el, mask, flags, cnt, entries);
    k_layer  <<<1024, 256, 0, stream>>>(cnt, entries, s0, att_w, edge_emb, s1, 0);
    k_layer  <<<1024, 256, 0, stream>>>(cnt, entries, s1, att_w, edge_emb, out, 1);
}